// Round 7
// baseline (209.322 us; speedup 1.0000x reference)
//
#include <hip/hip_runtime.h>

typedef unsigned short u16;
typedef unsigned int   u32;
typedef __bf16 bf16x8 __attribute__((ext_vector_type(8)));
typedef float  f32x4  __attribute__((ext_vector_type(4)));
typedef float  f32x2  __attribute__((ext_vector_type(2)));
typedef u32    u32x4  __attribute__((ext_vector_type(4)));
typedef u16    u16x4  __attribute__((ext_vector_type(4)));

#define D_MODEL 1024
#define T_SEQ   2048
#define NH      16
#define HD      64

// log2(e), Q pre-scale = 0.125*log2e, softmax C-init = -8*log2e
#define QSCALE  0.18033688011112042f
#define NEG8L2E -11.541560327111707f

__device__ __forceinline__ float b2f(u16 u){ return __uint_as_float(((u32)u)<<16); }
__device__ __forceinline__ u16 f2b(float f){
  u32 x = __float_as_uint(f);
  x += 0x7fffu + ((x>>16)&1u);
  return (u16)(x>>16);
}

// async global->LDS, 16B per lane. LDS ptr wave-uniform; HW adds lane*16.
__device__ __forceinline__ void gll16(const void* g, void* l){
  __builtin_amdgcn_global_load_lds((const __attribute__((address_space(1))) unsigned int*)g,
                                   (__attribute__((address_space(3))) unsigned int*)l, 16, 0, 0);
}

// ---------------- prep: X convert | weight transpose | rope table ----------------
__global__ __launch_bounds__(256) void prep(
    const float* __restrict__ X, u16* __restrict__ Xb,
    const float* __restrict__ W0, const float* __restrict__ W1,
    const float* __restrict__ W2, const float* __restrict__ W3,
    u16* __restrict__ T0, u16* __restrict__ T1,
    u16* __restrict__ T2, u16* __restrict__ T3,
    float* __restrict__ cs)
{
  __shared__ u16 s[32][33];
  const int id = blockIdx.x, tid = threadIdx.x;
  if (id < 4096){
    const int i = (id*256 + tid)<<2;
    f32x4 v = *(const f32x4*)(X + i);
    u16x4 o;
    o[0]=f2b(v[0]); o[1]=f2b(v[1]); o[2]=f2b(v[2]); o[3]=f2b(v[3]);
    *(u16x4*)(Xb + i) = o;
  } else if (id < 8192){
    const int wid = id - 4096;
    const int z = wid >> 10, tile = wid & 1023;
    const float* src = (z==0)?W0:(z==1)?W1:(z==2)?W2:W3;
    u16*         dst = (z==0)?T0:(z==1)?T1:(z==2)?T2:T3;
    const int x = tid & 31, y = tid >> 5;
    const int r0 = (tile>>5)*32, c0 = (tile&31)*32;
    #pragma unroll
    for (int r=0;r<4;r++) s[y + r*8][x] = f2b(src[(r0 + y + r*8)*D_MODEL + c0 + x]);
    __syncthreads();
    #pragma unroll
    for (int r=0;r<4;r++) dst[(c0 + y + r*8)*D_MODEL + r0 + x] = s[x][y + r*8];
  } else {
    const int gid = (id-8192)*256 + tid;   // 65536
    const int t = gid >> 5, fi = gid & 31;
    const float invf = expf(-(float)fi * 0.2878231366242558f);  // ln(1e4)/32
    float sn, cn;
    sincosf((float)t * invf, &sn, &cn);
    cs[gid*2]   = cn;
    cs[gid*2+1] = sn;
  }
}

// ============== QKV GEMM, BK=64, fused RMSNorm+RoPE epilogue ==============
// A[4096][1024] bf16, Bt[3072][1024] bf16 (WqT|WkT|WvT stacked).
// LDS slots: slot(row,c) = row*8 + (c ^ (row&7)), c = 16B chunk (8 bf16) of BK=64.
// grid 768 1D; XCD k=id&7 owns region bn in [(k&1)*12,+12), bm in [(k>>1)*8,+8).
// V is written TRANSPOSED per-head AND key-permuted within 64-token tiles:
//   slot(t) = (t&~63) + ((t&15)<<2) + ((t>>4)&3)   [matches attn P layout]
__global__ __launch_bounds__(256) void gemm_qkv(
    const u16* __restrict__ A, const u16* __restrict__ Bt,
    const float* __restrict__ qw, const float* __restrict__ kw,
    const float* __restrict__ cs,
    u16* __restrict__ Qb, u16* __restrict__ Kb, u16* __restrict__ Vt)
{
  __shared__ __align__(16) u16 sA[1024*8];   // 16 KB
  __shared__ __align__(16) u16 sB[1024*8];
  const int id = blockIdx.x;
  const int xcd = id & 7, slot = id >> 3;     // slot 0..95
  const int bn = (xcd & 1)*12 + (slot % 12);  // 0..23
  const int bm = (xcd >> 1)*8 + (slot / 12);  // 0..31
  const int bm0 = bm<<7, bn0 = bn<<7;

  const int tid = threadIdx.x;
  const int lane = tid & 63;
  const int w  = tid>>6;
  const int wm = (w>>1)<<6;
  const int wn = (w&1)<<6;
  const int quad = lane>>4, lr = lane&15;
  const int swl = lr & 7;

  int rS[4], cS[4];
  #pragma unroll
  for (int i=0;i<4;i++){
    int s = i*256 + tid;
    rS[i] = s>>3;
    cS[i] = (s&7) ^ (rS[i]&7);
  }

  const f32x4 z4 = {0.f,0.f,0.f,0.f};
  f32x4 acc[4][4];
  #pragma unroll
  for (int i=0;i<4;i++)
    #pragma unroll
    for (int j=0;j<4;j++) acc[i][j] = z4;

  for (int kt=0; kt<D_MODEL; kt+=64){
    #pragma unroll
    for (int i=0;i<4;i++)
      gll16(A  + (bm0+rS[i])*D_MODEL + kt + cS[i]*8, sA + (i*256 + w*64)*8);
    #pragma unroll
    for (int i=0;i<4;i++)
      gll16(Bt + (bn0+rS[i])*D_MODEL + kt + cS[i]*8, sB + (i*256 + w*64)*8);
    __syncthreads();
    #pragma unroll
    for (int kk=0; kk<2; ++kk){
      bf16x8 af[4], bfr[4];
      const int cq = (kk*4 + quad) ^ swl;
      #pragma unroll
      for (int i=0;i<4;i++) af[i]  = *(const bf16x8*)(sA + ((wm + (i<<4) + lr)*8 + cq)*8);
      #pragma unroll
      for (int j=0;j<4;j++) bfr[j] = *(const bf16x8*)(sB + ((wn + (j<<4) + lr)*8 + cq)*8);
      #pragma unroll
      for (int i=0;i<4;i++)
        #pragma unroll
        for (int j=0;j<4;j++)
          acc[i][j] = __builtin_amdgcn_mfma_f32_16x16x32_bf16(af[i], bfr[j], acc[i][j], 0, 0, 0);
    }
    __syncthreads();
  }

  const int z = bn0 >> 10;          // 0=Q, 1=K, 2=V
  const int ncl = bn0 & 1023;
  const int rq = quad<<2;

  if (z == 2){
    #pragma unroll
    for (int i=0;i<4;i++){
      int row0 = bm0 + wm + (i<<4) + rq;
      int bb = row0 >> 11, tt = row0 & (T_SEQ-1);
      #pragma unroll
      for (int j=0;j<4;j++){
        int nv = ncl + wn + (j<<4) + lr;
        int hh = nv >> 6, dd = nv & 63;
        u16* basep = Vt + ((bb*NH + hh)*HD + dd)*T_SEQ;
        #pragma unroll
        for (int r=0;r<4;r++){
          int t = tt + r;
          int pt = (t & ~63) + ((t&15)<<2) + ((t>>4)&3);
          basep[pt] = f2b(acc[i][j][r]);
        }
      }
    }
  } else {
    const float* w_ = (z==0) ? qw : kw;
    u16* dst = (z==0) ? Qb : Kb;
    const float scale = (z==0) ? QSCALE : 1.0f;
    float wv[4];
    #pragma unroll
    for (int j=0;j<4;j++) wv[j] = w_[(j<<4) + lr];
    #pragma unroll
    for (int i=0;i<4;i++){
      #pragma unroll
      for (int r=0;r<4;r++){
        const int grow = bm0 + wm + (i<<4) + rq + r;
        float ss = 0.f;
        #pragma unroll
        for (int j=0;j<4;j++) ss += acc[i][j][r]*acc[i][j][r];
        #pragma unroll
        for (int off=8; off>=1; off>>=1) ss += __shfl_xor(ss, off, 64);
        const float rms = rsqrtf(ss*(1.0f/64.0f) + 1e-6f);
        float xn[4];
        #pragma unroll
        for (int j=0;j<4;j++) xn[j] = acc[i][j][r]*rms*wv[j];
        const int t = grow & (T_SEQ-1);
        f32x2 c0 = *(const f32x2*)(cs + (t*32 + lr)*2);
        f32x2 c1 = *(const f32x2*)(cs + (t*32 + 16 + lr)*2);
        float o0 = xn[0]*c0[0] - xn[2]*c0[1];
        float o2 = xn[2]*c0[0] + xn[0]*c0[1];
        float o1 = xn[1]*c1[0] - xn[3]*c1[1];
        float o3 = xn[3]*c1[0] + xn[1]*c1[1];
        u16* rp = dst + grow*D_MODEL + ncl + wn + lr;
        rp[0]  = f2b(o0*scale);
        rp[16] = f2b(o1*scale);
        rp[32] = f2b(o2*scale);
        rp[48] = f2b(o3*scale);
      }
    }
  }
}

// ============== output GEMM, BK=64, f32 out ==============
__global__ __launch_bounds__(256) void gemm_out(
    const u16* __restrict__ A, const u16* __restrict__ Bt, float* __restrict__ out)
{
  __shared__ __align__(16) u16 sA[1024*8];
  __shared__ __align__(16) u16 sB[1024*8];
  const int id = blockIdx.x;
  const int xcd = id & 7, slot = id >> 3;
  const int bn = slot & 7;
  const int bm = xcd*4 + (slot>>3);
  const int bm0 = bm<<7, bn0 = bn<<7;

  const int tid = threadIdx.x;
  const int lane = tid & 63;
  const int w  = tid>>6;
  const int wm = (w>>1)<<6;
  const int wn = (w&1)<<6;
  const int quad = lane>>4, lr = lane&15;
  const int swl = lr & 7;

  int rS[4], cS[4];
  #pragma unroll
  for (int i=0;i<4;i++){
    int s = i*256 + tid;
    rS[i] = s>>3;
    cS[i] = (s&7) ^ (rS[i]&7);
  }

  const f32x4 z4 = {0.f,0.f,0.f,0.f};
  f32x4 acc[4][4];
  #pragma unroll
  for (int i=0;i<4;i++)
    #pragma unroll
    for (int j=0;j<4;j++) acc[i][j] = z4;

  for (int kt=0; kt<D_MODEL; kt+=64){
    #pragma unroll
    for (int i=0;i<4;i++)
      gll16(A  + (bm0+rS[i])*D_MODEL + kt + cS[i]*8, sA + (i*256 + w*64)*8);
    #pragma unroll
    for (int i=0;i<4;i++)
      gll16(Bt + (bn0+rS[i])*D_MODEL + kt + cS[i]*8, sB + (i*256 + w*64)*8);
    __syncthreads();
    #pragma unroll
    for (int kk=0; kk<2; ++kk){
      bf16x8 af[4], bfr[4];
      const int cq = (kk*4 + quad) ^ swl;
      #pragma unroll
      for (int i=0;i<4;i++) af[i]  = *(const bf16x8*)(sA + ((wm + (i<<4) + lr)*8 + cq)*8);
      #pragma unroll
      for (int j=0;j<4;j++) bfr[j] = *(const bf16x8*)(sB + ((wn + (j<<4) + lr)*8 + cq)*8);
      #pragma unroll
      for (int i=0;i<4;i++)
        #pragma unroll
        for (int j=0;j<4;j++)
          acc[i][j] = __builtin_amdgcn_mfma_f32_16x16x32_bf16(af[i], bfr[j], acc[i][j], 0, 0, 0);
    }
    __syncthreads();
  }

  const int rq = quad<<2;
  #pragma unroll
  for (int i=0;i<4;i++){
    #pragma unroll
    for (int r=0;r<4;r++){
      const int grow = bm0 + wm + (i<<4) + rq + r;
      #pragma unroll
      for (int j=0;j<4;j++)
        out[grow*D_MODEL + bn0 + wn + (j<<4) + lr] = acc[i][j][r];
    }
  }
}

// ---------------- MFMA flash attention: 128 q-rows/block, 32 rows/wave ----------
// Q pre-scaled by 0.125*log2e => p = exp2(s - 8*log2e), no running max.
// K/VT tiles: slot(row,c) = row*8 + (c^(row&7)), c = 16B chunk.
// P per wave: [32 rows][64 key-slots] u16, key-slot s = (kappa&15)*4 + (kappa>>4)
// (V stored with same permutation in global), chunk-XOR by (row&7).
__global__ __launch_bounds__(256) void attn_mfma(const u16* __restrict__ Qb, const u16* __restrict__ Kb,
                                                 const u16* __restrict__ Vt, u16* __restrict__ AO)
{
  __shared__ __align__(16) u16 sK [2][4096];   // 8 KB each
  __shared__ __align__(16) u16 sVT[2][4096];
  __shared__ __align__(16) u16 sP [4][2048];   // 4 KB per wave
  const int tid = threadIdx.x;
  const int h  = blockIdx.x, b = blockIdx.y;
  const int zb = blockIdx.z;
  const int qt = (zb < 8) ? (15 - zb) : (zb - 8);   // balanced pairs
  const int w = tid>>6, lane = tid&63;
  const int quad = lane>>4, lr = lane&15;
  const int q8 = quad<<3;

  const int s0 = w*64 + lane, s1 = 256 + w*64 + lane;
  const int r0s = s0>>3, c0s = (s0&7)^(r0s&7);
  const int r1s = s1>>3, c1s = (s1&7)^(r1s&7);
  const u16* Kbase = Kb + (b*T_SEQ)*D_MODEL + h*HD;
  const u16* Vbase = Vt + (b*NH + h)*HD*T_SEQ;
  const int ldsOff0 = (w*64)*8, ldsOff1 = (256 + w*64)*8;

  // Q fragments: wave owns rows qt*128 + w*32 + {0..31} (2 strips of 16)
  bf16x8 qf[2][2];
  #pragma unroll
  for (int s=0;s<2;s++){
    const u16* Qrow = Qb + (b*T_SEQ + qt*128 + w*32 + s*16 + lr)*D_MODEL + h*HD;
    qf[s][0] = *(const bf16x8*)(Qrow + q8);
    qf[s][1] = *(const bf16x8*)(Qrow + 32 + q8);
  }

  f32x4 o[2][4];
  float lp[2][4];
  const f32x4 z4 = {0.f,0.f,0.f,0.f};
  const f32x4 ci = {NEG8L2E, NEG8L2E, NEG8L2E, NEG8L2E};
  #pragma unroll
  for (int s=0;s<2;s++)
    #pragma unroll
    for (int r=0;r<4;r++){ lp[s][r] = 0.f; }
  #pragma unroll
  for (int s=0;s<2;s++)
    #pragma unroll
    for (int nt=0;nt<4;nt++) o[s][nt] = z4;

  u16* myP = sP[w];
  const int nk = 2*qt + 2;   // number of 64-key tiles

  gll16(Kbase + r0s*D_MODEL + c0s*8, &sK[0][ldsOff0]);
  gll16(Kbase + r1s*D_MODEL + c1s*8, &sK[0][ldsOff1]);
  gll16(Vbase + r0s*T_SEQ + c0s*8,   &sVT[0][ldsOff0]);
  gll16(Vbase + r1s*T_SEQ + c1s*8,   &sVT[0][ldsOff1]);
  __syncthreads();

  for (int kt=0; kt<nk; ++kt){
    const int cur = kt&1;
    if (kt+1 < nk){
      const int kn = kt+1, nb = cur^1;
      gll16(Kbase + (kn*64 + r0s)*D_MODEL + c0s*8, &sK[nb][ldsOff0]);
      gll16(Kbase + (kn*64 + r1s)*D_MODEL + c1s*8, &sK[nb][ldsOff1]);
      gll16(Vbase + r0s*T_SEQ + kn*64 + c0s*8,     &sVT[nb][ldsOff0]);
      gll16(Vbase + r1s*T_SEQ + kn*64 + c1s*8,     &sVT[nb][ldsOff1]);
    }

    // S = Q K^T for both strips (C-init -8*log2e)
    f32x4 s4[2][4];
    #pragma unroll
    for (int ct=0; ct<4; ++ct){
      const int row = ct*16 + lr;
      const int sw = row&7;
      bf16x8 k0 = *(const bf16x8*)(&sK[cur][(row*8 + (quad     ^ sw))*8]);
      bf16x8 k1 = *(const bf16x8*)(&sK[cur][(row*8 + ((4+quad) ^ sw))*8]);
      #pragma unroll
      for (int s=0;s<2;s++){
        f32x4 acc = ci;
        acc = __builtin_amdgcn_mfma_f32_16x16x32_bf16(qf[s][0], k0, acc, 0,0,0);
        acc = __builtin_amdgcn_mfma_f32_16x16x32_bf16(qf[s][1], k1, acc, 0,0,0);
        s4[s][ct] = acc;
      }
    }

    if (kt >= nk-2){   // diagonal region
      #pragma unroll
      for (int ct=0; ct<4; ++ct){
        const int colg = kt*64 + ct*16 + lr;
        #pragma unroll
        for (int s=0;s<2;s++){
          const int rowb = qt*128 + w*32 + s*16 + quad*4;
          #pragma unroll
          for (int r=0;r<4;r++)
            if (colg > rowb + r) s4[s][ct][r] = -1e30f;
        }
      }
    }

    // p = exp2(s); truncate to bf16 consistently; vectorized P write (b64)
    #pragma unroll
    for (int s=0;s<2;s++){
      #pragma unroll
      for (int r=0;r<4;r++){
        u16x4 pk;
        #pragma unroll
        for (int ct=0; ct<4; ++ct){
          float p = exp2f(s4[s][ct][r]);
          u32 pu = __float_as_uint(p) & 0xffff0000u;
          lp[s][r] += __uint_as_float(pu);
          pk[ct] = (u16)(pu>>16);
        }
        const int prow = s*16 + quad*4 + r;
        const int pidx = prow*64 + (((lr>>1) ^ (prow&7))<<3) + ((lr&1)<<2);
        *(u16x4*)(myP + pidx) = pk;
      }
    }

    // O += P V (key-slot order matches permuted V)
    #pragma unroll
    for (int st=0; st<2; ++st){
      bf16x8 pf[2];
      #pragma unroll
      for (int s=0;s<2;s++){
        const int prow = s*16 + lr;
        pf[s] = *(const bf16x8*)(myP + prow*64 + (((st*4+quad) ^ (lr&7))<<3));
      }
      #pragma unroll
      for (int nt=0;nt<4;nt++){
        const int row = nt*16 + lr;
        const int slotv = row*8 + ((st*4+quad) ^ (row&7));
        bf16x8 vf = *(const bf16x8*)(&sVT[cur][slotv*8]);
        #pragma unroll
        for (int s=0;s<2;s++)
          o[s][nt] = __builtin_amdgcn_mfma_f32_16x16x32_bf16(pf[s], vf, o[s][nt], 0,0,0);
      }
    }
    __syncthreads();
  }

  #pragma unroll
  for (int s=0;s<2;s++)
    #pragma unroll
    for (int r=0;r<4;r++){
      #pragma unroll
      for (int off=8; off>=1; off>>=1) lp[s][r] += __shfl_xor(lp[s][r], off, 64);
    }
  #pragma unroll
  for (int s=0;s<2;s++){
    const int rowg = b*T_SEQ + qt*128 + w*32 + s*16 + quad*4;
    #pragma unroll
    for (int r=0;r<4;r++){
      float inv = 1.0f / lp[s][r];
      #pragma unroll
      for (int nt=0;nt<4;nt++)
        AO[(rowg + r)*D_MODEL + h*HD + nt*16 + lr] = f2b(o[s][nt][r]*inv);
    }
  }
}

extern "C" void kernel_launch(void* const* d_in, const int* in_sizes, int n_in,
                              void* d_out, int out_size, void* d_ws, size_t ws_size,
                              hipStream_t stream)
{
  const float* X  = (const float*)d_in[0];
  const float* Wq = (const float*)d_in[1];
  const float* Wk = (const float*)d_in[2];
  const float* Wv = (const float*)d_in[3];
  const float* Wo = (const float*)d_in[4];
  const float* qw = (const float*)d_in[5];
  const float* kw = (const float*)d_in[6];

  char* ws = (char*)d_ws;
  const size_t MB = 1024*1024;
  u16*   WqkvT = (u16*)(ws + 0*MB);        // 6 MB
  u16*   WoT   = (u16*)(ws + 6*MB);        // 2 MB
  u16*   Xb    = (u16*)(ws + 8*MB);        // 8 MB
  u16*   Qb    = (u16*)(ws + 16*MB);       // 8 MB
  u16*   Kb    = (u16*)(ws + 24*MB);       // 8 MB
  u16*   Vt    = (u16*)(ws + 32*MB);       // 8 MB (transposed + key-permuted)
  u16*   AO    = (u16*)(ws + 40*MB);       // 8 MB
  float* CS    = (float*)(ws + 48*MB);     // 512 KB rope table

  prep<<<dim3(8448), 256, 0, stream>>>(X, Xb, Wq, Wk, Wv, Wo,
      WqkvT, WqkvT + 1024*1024, WqkvT + 2*1024*1024, WoT, CS);
  gemm_qkv<<<dim3(768), 256, 0, stream>>>(Xb, WqkvT, qw, kw, CS, Qb, Kb, Vt);
  attn_mfma<<<dim3(NH, 2, 16), 256, 0, stream>>>(Qb, Kb, Vt, AO);
  gemm_out<<<dim3(256), 256, 0, stream>>>(AO, WoT, (float*)d_out);
}

// Round 8
// 185.904 us; speedup vs baseline: 1.1260x; 1.1260x over previous
//
#include <hip/hip_runtime.h>

typedef unsigned short u16;
typedef unsigned int   u32;
typedef __bf16 bf16x8 __attribute__((ext_vector_type(8)));
typedef float  f32x4  __attribute__((ext_vector_type(4)));
typedef float  f32x2  __attribute__((ext_vector_type(2)));
typedef u32    u32x4  __attribute__((ext_vector_type(4)));
typedef u16    u16x4  __attribute__((ext_vector_type(4)));

#define D_MODEL 1024
#define T_SEQ   2048
#define NH      16
#define HD      64

// log2(e), Q pre-scale = 0.125*log2e, softmax C-init = -8*log2e
#define QSCALE  0.18033688011112042f
#define NEG8L2E -11.541560327111707f

__device__ __forceinline__ float b2f(u16 u){ return __uint_as_float(((u32)u)<<16); }
__device__ __forceinline__ u16 f2b(float f){
  u32 x = __float_as_uint(f);
  x += 0x7fffu + ((x>>16)&1u);
  return (u16)(x>>16);
}

// async global->LDS, 16B per lane. LDS ptr wave-uniform; HW adds lane*16.
__device__ __forceinline__ void gll16(const void* g, void* l){
  __builtin_amdgcn_global_load_lds((const __attribute__((address_space(1))) unsigned int*)g,
                                   (__attribute__((address_space(3))) unsigned int*)l, 16, 0, 0);
}

// ---------------- prep: X convert | weight transpose | rope table ----------------
__global__ __launch_bounds__(256) void prep(
    const float* __restrict__ X, u16* __restrict__ Xb,
    const float* __restrict__ W0, const float* __restrict__ W1,
    const float* __restrict__ W2, const float* __restrict__ W3,
    u16* __restrict__ T0, u16* __restrict__ T1,
    u16* __restrict__ T2, u16* __restrict__ T3,
    float* __restrict__ cs)
{
  __shared__ u16 s[32][33];
  const int id = blockIdx.x, tid = threadIdx.x;
  if (id < 4096){
    const int i = (id*256 + tid)<<2;
    f32x4 v = *(const f32x4*)(X + i);
    u16x4 o;
    o[0]=f2b(v[0]); o[1]=f2b(v[1]); o[2]=f2b(v[2]); o[3]=f2b(v[3]);
    *(u16x4*)(Xb + i) = o;
  } else if (id < 8192){
    const int wid = id - 4096;
    const int z = wid >> 10, tile = wid & 1023;
    const float* src = (z==0)?W0:(z==1)?W1:(z==2)?W2:W3;
    u16*         dst = (z==0)?T0:(z==1)?T1:(z==2)?T2:T3;
    const int x = tid & 31, y = tid >> 5;
    const int r0 = (tile>>5)*32, c0 = (tile&31)*32;
    #pragma unroll
    for (int r=0;r<4;r++) s[y + r*8][x] = f2b(src[(r0 + y + r*8)*D_MODEL + c0 + x]);
    __syncthreads();
    #pragma unroll
    for (int r=0;r<4;r++) dst[(c0 + y + r*8)*D_MODEL + r0 + x] = s[x][y + r*8];
  } else {
    const int gid = (id-8192)*256 + tid;   // 65536
    const int t = gid >> 5, fi = gid & 31;
    const float invf = expf(-(float)fi * 0.2878231366242558f);  // ln(1e4)/32
    float sn, cn;
    sincosf((float)t * invf, &sn, &cn);
    cs[gid*2]   = cn;
    cs[gid*2+1] = sn;
  }
}

// ============== QKV GEMM, BK=64, fused RMSNorm+RoPE epilogue ==============
// A[4096][1024] bf16, Bt[3072][1024] bf16 (WqT|WkT|WvT stacked).
// LDS slots: slot(row,c) = row*8 + (c ^ (row&7)), c = 16B chunk (8 bf16) of BK=64.
// grid 768 1D; XCD k=id&7 owns region bn in [(k&1)*12,+12), bm in [(k>>1)*8,+8).
// V written TRANSPOSED per-head AND key-permuted within 64-token tiles:
//   slot(t) = (t&~63) + ((t&15)<<2) + ((t>>4)&3)   [matches attn P layout]
__global__ __launch_bounds__(256) void gemm_qkv(
    const u16* __restrict__ A, const u16* __restrict__ Bt,
    const float* __restrict__ qw, const float* __restrict__ kw,
    const float* __restrict__ cs,
    u16* __restrict__ Qb, u16* __restrict__ Kb, u16* __restrict__ Vt)
{
  __shared__ __align__(16) u16 sA[1024*8];   // 16 KB
  __shared__ __align__(16) u16 sB[1024*8];
  const int id = blockIdx.x;
  const int xcd = id & 7, slot = id >> 3;     // slot 0..95
  const int bn = (xcd & 1)*12 + (slot % 12);  // 0..23
  const int bm = (xcd >> 1)*8 + (slot / 12);  // 0..31
  const int bm0 = bm<<7, bn0 = bn<<7;

  const int tid = threadIdx.x;
  const int lane = tid & 63;
  const int w  = tid>>6;
  const int wm = (w>>1)<<6;
  const int wn = (w&1)<<6;
  const int quad = lane>>4, lr = lane&15;
  const int swl = lr & 7;

  int rS[4], cS[4];
  #pragma unroll
  for (int i=0;i<4;i++){
    int s = i*256 + tid;
    rS[i] = s>>3;
    cS[i] = (s&7) ^ (rS[i]&7);
  }

  const f32x4 z4 = {0.f,0.f,0.f,0.f};
  f32x4 acc[4][4];
  #pragma unroll
  for (int i=0;i<4;i++)
    #pragma unroll
    for (int j=0;j<4;j++) acc[i][j] = z4;

  for (int kt=0; kt<D_MODEL; kt+=64){
    #pragma unroll
    for (int i=0;i<4;i++)
      gll16(A  + (bm0+rS[i])*D_MODEL + kt + cS[i]*8, sA + (i*256 + w*64)*8);
    #pragma unroll
    for (int i=0;i<4;i++)
      gll16(Bt + (bn0+rS[i])*D_MODEL + kt + cS[i]*8, sB + (i*256 + w*64)*8);
    __syncthreads();
    #pragma unroll
    for (int kk=0; kk<2; ++kk){
      bf16x8 af[4], bfr[4];
      const int cq = (kk*4 + quad) ^ swl;
      #pragma unroll
      for (int i=0;i<4;i++) af[i]  = *(const bf16x8*)(sA + ((wm + (i<<4) + lr)*8 + cq)*8);
      #pragma unroll
      for (int j=0;j<4;j++) bfr[j] = *(const bf16x8*)(sB + ((wn + (j<<4) + lr)*8 + cq)*8);
      #pragma unroll
      for (int i=0;i<4;i++)
        #pragma unroll
        for (int j=0;j<4;j++)
          acc[i][j] = __builtin_amdgcn_mfma_f32_16x16x32_bf16(af[i], bfr[j], acc[i][j], 0, 0, 0);
    }
    __syncthreads();
  }

  const int z = bn0 >> 10;          // 0=Q, 1=K, 2=V
  const int ncl = bn0 & 1023;
  const int rq = quad<<2;

  if (z == 2){
    #pragma unroll
    for (int i=0;i<4;i++){
      int row0 = bm0 + wm + (i<<4) + rq;
      int bb = row0 >> 11, tt = row0 & (T_SEQ-1);
      #pragma unroll
      for (int j=0;j<4;j++){
        int nv = ncl + wn + (j<<4) + lr;
        int hh = nv >> 6, dd = nv & 63;
        u16* basep = Vt + ((bb*NH + hh)*HD + dd)*T_SEQ;
        #pragma unroll
        for (int r=0;r<4;r++){
          int t = tt + r;
          int pt = (t & ~63) + ((t&15)<<2) + ((t>>4)&3);
          basep[pt] = f2b(acc[i][j][r]);
        }
      }
    }
  } else {
    const float* w_ = (z==0) ? qw : kw;
    u16* dst = (z==0) ? Qb : Kb;
    const float scale = (z==0) ? QSCALE : 1.0f;
    float wv[4];
    #pragma unroll
    for (int j=0;j<4;j++) wv[j] = w_[(j<<4) + lr];
    #pragma unroll
    for (int i=0;i<4;i++){
      #pragma unroll
      for (int r=0;r<4;r++){
        const int grow = bm0 + wm + (i<<4) + rq + r;
        float ss = 0.f;
        #pragma unroll
        for (int j=0;j<4;j++) ss += acc[i][j][r]*acc[i][j][r];
        #pragma unroll
        for (int off=8; off>=1; off>>=1) ss += __shfl_xor(ss, off, 64);
        const float rms = rsqrtf(ss*(1.0f/64.0f) + 1e-6f);
        float xn[4];
        #pragma unroll
        for (int j=0;j<4;j++) xn[j] = acc[i][j][r]*rms*wv[j];
        const int t = grow & (T_SEQ-1);
        f32x2 c0 = *(const f32x2*)(cs + (t*32 + lr)*2);
        f32x2 c1 = *(const f32x2*)(cs + (t*32 + 16 + lr)*2);
        float o0 = xn[0]*c0[0] - xn[2]*c0[1];
        float o2 = xn[2]*c0[0] + xn[0]*c0[1];
        float o1 = xn[1]*c1[0] - xn[3]*c1[1];
        float o3 = xn[3]*c1[0] + xn[1]*c1[1];
        u16* rp = dst + grow*D_MODEL + ncl + wn + lr;
        rp[0]  = f2b(o0*scale);
        rp[16] = f2b(o1*scale);
        rp[32] = f2b(o2*scale);
        rp[48] = f2b(o3*scale);
      }
    }
  }
}

// ============== output GEMM: 64x128 tiles, BK=64, f32 out ==============
// grid 512 1D; XCD k=id&7 owns bm in [k*8, k*8+8), all 8 bn.
__global__ __launch_bounds__(256) void gemm_out(
    const u16* __restrict__ A, const u16* __restrict__ Bt, float* __restrict__ out)
{
  __shared__ __align__(16) u16 sA[512*8];    // 8 KB (64 rows)
  __shared__ __align__(16) u16 sB[1024*8];   // 16 KB (128 rows)
  const int id = blockIdx.x;
  const int xcd = id & 7, slot = id >> 3;    // slot 0..63
  const int bm = xcd*8 + (slot>>3);          // 0..63 (64-row tiles)
  const int bn = slot & 7;                   // 0..7  (128-col tiles)
  const int bm0 = bm<<6, bn0 = bn<<7;

  const int tid = threadIdx.x;
  const int lane = tid & 63;
  const int w  = tid>>6;
  const int wm = (w>>1)<<5;    // 0/32
  const int wn = (w&1)<<6;     // 0/64
  const int quad = lane>>4, lr = lane&15;
  const int swl = lr & 7;

  int rS[4], cS[4];
  #pragma unroll
  for (int i=0;i<4;i++){
    int s = i*256 + tid;
    rS[i] = s>>3;
    cS[i] = (s&7) ^ (rS[i]&7);
  }

  const f32x4 z4 = {0.f,0.f,0.f,0.f};
  f32x4 acc[2][4];
  #pragma unroll
  for (int i=0;i<2;i++)
    #pragma unroll
    for (int j=0;j<4;j++) acc[i][j] = z4;

  for (int kt=0; kt<D_MODEL; kt+=64){
    #pragma unroll
    for (int i=0;i<2;i++)
      gll16(A  + (bm0+rS[i])*D_MODEL + kt + cS[i]*8, sA + (i*256 + w*64)*8);
    #pragma unroll
    for (int i=0;i<4;i++)
      gll16(Bt + (bn0+rS[i])*D_MODEL + kt + cS[i]*8, sB + (i*256 + w*64)*8);
    __syncthreads();
    #pragma unroll
    for (int kk=0; kk<2; ++kk){
      bf16x8 af[2], bfr[4];
      const int cq = (kk*4 + quad) ^ swl;
      #pragma unroll
      for (int i=0;i<2;i++) af[i]  = *(const bf16x8*)(sA + ((wm + (i<<4) + lr)*8 + cq)*8);
      #pragma unroll
      for (int j=0;j<4;j++) bfr[j] = *(const bf16x8*)(sB + ((wn + (j<<4) + lr)*8 + cq)*8);
      #pragma unroll
      for (int i=0;i<2;i++)
        #pragma unroll
        for (int j=0;j<4;j++)
          acc[i][j] = __builtin_amdgcn_mfma_f32_16x16x32_bf16(af[i], bfr[j], acc[i][j], 0, 0, 0);
    }
    __syncthreads();
  }

  const int rq = quad<<2;
  #pragma unroll
  for (int i=0;i<2;i++){
    #pragma unroll
    for (int r=0;r<4;r++){
      const int grow = bm0 + wm + (i<<4) + rq + r;
      #pragma unroll
      for (int j=0;j<4;j++)
        out[grow*D_MODEL + bn0 + wn + (j<<4) + lr] = acc[i][j][r];
    }
  }
}

// ---------------- MFMA flash attention: 64 q-rows/block, 16 rows/wave ----------
// Q pre-scaled by 0.125*log2e => p = exp2(s - 8*log2e), no running max.
// K/VT tiles: slot(row,c) = row*8 + (c^(row&7)), c = 16B chunk.
// P per wave: [16 rows][64 key-slots] u16, key-slot s = (kappa&15)*4 + (kappa>>4)
// (V stored with same permutation in global), chunk-XOR by (row&7).
// LDS total = 16K + 16K + 8K = 40960 B -> 4 blocks/CU.
__global__ __launch_bounds__(256) void attn_mfma(const u16* __restrict__ Qb, const u16* __restrict__ Kb,
                                                 const u16* __restrict__ Vt, u16* __restrict__ AO)
{
  __shared__ __align__(16) u16 sK [2][4096];   // 8 KB each
  __shared__ __align__(16) u16 sVT[2][4096];
  __shared__ __align__(16) u16 sP [4][1024];   // 2 KB per wave
  const int tid = threadIdx.x;
  const int h  = blockIdx.x, b = blockIdx.y;
  const int qt = 31 - blockIdx.z;            // largest-first
  const int w = tid>>6, lane = tid&63;
  const int quad = lane>>4, lr = lane&15;
  const int q8 = quad<<3;

  const int s0 = w*64 + lane, s1 = 256 + w*64 + lane;
  const int r0s = s0>>3, c0s = (s0&7)^(r0s&7);
  const int r1s = s1>>3, c1s = (s1&7)^(r1s&7);
  const u16* Kbase = Kb + (b*T_SEQ)*D_MODEL + h*HD;
  const u16* Vbase = Vt + (b*NH + h)*HD*T_SEQ;
  const int ldsOff0 = (w*64)*8, ldsOff1 = (256 + w*64)*8;

  const u16* Qrow = Qb + (b*T_SEQ + qt*64 + w*16 + lr)*D_MODEL + h*HD;
  bf16x8 qf0 = *(const bf16x8*)(Qrow + q8);
  bf16x8 qf1 = *(const bf16x8*)(Qrow + 32 + q8);

  f32x4 o[4];
  float lp[4];
  const f32x4 z4 = {0.f,0.f,0.f,0.f};
  const f32x4 ci = {NEG8L2E, NEG8L2E, NEG8L2E, NEG8L2E};
  #pragma unroll
  for (int r=0;r<4;r++) lp[r] = 0.f;
  #pragma unroll
  for (int nt=0;nt<4;nt++) o[nt] = z4;

  u16* myP = sP[w];

  gll16(Kbase + r0s*D_MODEL + c0s*8, &sK[0][ldsOff0]);
  gll16(Kbase + r1s*D_MODEL + c1s*8, &sK[0][ldsOff1]);
  gll16(Vbase + r0s*T_SEQ + c0s*8,   &sVT[0][ldsOff0]);
  gll16(Vbase + r1s*T_SEQ + c1s*8,   &sVT[0][ldsOff1]);
  __syncthreads();

  for (int kt=0; kt<=qt; ++kt){
    const int cur = kt&1;
    if (kt < qt){
      const int kn = kt+1, nb = cur^1;
      gll16(Kbase + (kn*64 + r0s)*D_MODEL + c0s*8, &sK[nb][ldsOff0]);
      gll16(Kbase + (kn*64 + r1s)*D_MODEL + c1s*8, &sK[nb][ldsOff1]);
      gll16(Vbase + r0s*T_SEQ + kn*64 + c0s*8,     &sVT[nb][ldsOff0]);
      gll16(Vbase + r1s*T_SEQ + kn*64 + c1s*8,     &sVT[nb][ldsOff1]);
    }

    // S = Q K^T (C-init -8*log2e)
    f32x4 s4[4];
    #pragma unroll
    for (int ct=0; ct<4; ++ct){
      const int row = ct*16 + lr;
      const int sw = row&7;
      bf16x8 k0 = *(const bf16x8*)(&sK[cur][(row*8 + (quad     ^ sw))*8]);
      bf16x8 k1 = *(const bf16x8*)(&sK[cur][(row*8 + ((4+quad) ^ sw))*8]);
      f32x4 acc = ci;
      acc = __builtin_amdgcn_mfma_f32_16x16x32_bf16(qf0, k0, acc, 0,0,0);
      acc = __builtin_amdgcn_mfma_f32_16x16x32_bf16(qf1, k1, acc, 0,0,0);
      s4[ct] = acc;
    }

    if (kt == qt){
      #pragma unroll
      for (int ct=0; ct<4; ++ct){
        int col = ct*16 + lr;
        #pragma unroll
        for (int r=0;r<4;r++)
          if (col > w*16 + quad*4 + r) s4[ct][r] = -1e30f;
      }
    }

    // p = exp2(s); truncate to bf16 consistently; vectorized P write (b64)
    #pragma unroll
    for (int r=0;r<4;r++){
      u16x4 pk;
      #pragma unroll
      for (int ct=0; ct<4; ++ct){
        float p = exp2f(s4[ct][r]);
        u32 pu = __float_as_uint(p) & 0xffff0000u;
        lp[r] += __uint_as_float(pu);
        pk[ct] = (u16)(pu>>16);
      }
      const int prow = quad*4 + r;
      const int pidx = prow*64 + (((lr>>1) ^ (prow&7))<<3) + ((lr&1)<<2);
      *(u16x4*)(myP + pidx) = pk;
    }

    // O += P V (key-slot order matches permuted V)
    #pragma unroll
    for (int st=0; st<2; ++st){
      bf16x8 pf = *(const bf16x8*)(myP + lr*64 + (((st*4+quad) ^ (lr&7))<<3));
      #pragma unroll
      for (int nt=0;nt<4;nt++){
        const int row = nt*16 + lr;
        const int slotv = row*8 + ((st*4+quad) ^ (row&7));
        bf16x8 vf = *(const bf16x8*)(&sVT[cur][slotv*8]);
        o[nt] = __builtin_amdgcn_mfma_f32_16x16x32_bf16(pf, vf, o[nt], 0,0,0);
      }
    }
    __syncthreads();
  }

  #pragma unroll
  for (int r=0;r<4;r++){
    #pragma unroll
    for (int off=8; off>=1; off>>=1) lp[r] += __shfl_xor(lp[r], off, 64);
  }
  const int rowg = b*T_SEQ + qt*64 + w*16 + quad*4;
  #pragma unroll
  for (int r=0;r<4;r++){
    float inv = 1.0f / lp[r];
    #pragma unroll
    for (int nt=0;nt<4;nt++)
      AO[(rowg + r)*D_MODEL + h*HD + nt*16 + lr] = f2b(o[nt][r]*inv);
  }
}

extern "C" void kernel_launch(void* const* d_in, const int* in_sizes, int n_in,
                              void* d_out, int out_size, void* d_ws, size_t ws_size,
                              hipStream_t stream)
{
  const float* X  = (const float*)d_in[0];
  const float* Wq = (const float*)d_in[1];
  const float* Wk = (const float*)d_in[2];
  const float* Wv = (const float*)d_in[3];
  const float* Wo = (const float*)d_in[4];
  const float* qw = (const float*)d_in[5];
  const float* kw = (const float*)d_in[6];

  char* ws = (char*)d_ws;
  const size_t MB = 1024*1024;
  u16*   WqkvT = (u16*)(ws + 0*MB);        // 6 MB
  u16*   WoT   = (u16*)(ws + 6*MB);        // 2 MB
  u16*   Xb    = (u16*)(ws + 8*MB);        // 8 MB
  u16*   Qb    = (u16*)(ws + 16*MB);       // 8 MB
  u16*   Kb    = (u16*)(ws + 24*MB);       // 8 MB
  u16*   Vt    = (u16*)(ws + 32*MB);       // 8 MB (transposed + key-permuted)
  u16*   AO    = (u16*)(ws + 40*MB);       // 8 MB
  float* CS    = (float*)(ws + 48*MB);     // 512 KB rope table

  prep<<<dim3(8448), 256, 0, stream>>>(X, Xb, Wq, Wk, Wv, Wo,
      WqkvT, WqkvT + 1024*1024, WqkvT + 2*1024*1024, WoT, CS);
  gemm_qkv<<<dim3(768), 256, 0, stream>>>(Xb, WqkvT, qw, kw, CS, Qb, Kb, Vt);
  attn_mfma<<<dim3(NH, 2, 32), 256, 0, stream>>>(Qb, Kb, Vt, AO);
  gemm_out<<<dim3(512), 256, 0, stream>>>(AO, WoT, (float*)d_out);
}